// Round 8
// baseline (433.284 us; speedup 1.0000x reference)
//
#include <hip/hip_runtime.h>
#include <math.h>

namespace {

typedef unsigned short ushort_t;
typedef unsigned int uint_t;
typedef unsigned char uchar_t;
typedef __attribute__((ext_vector_type(4))) float f32x4;

constexpr int NBATCH = 16;
constexpr int NCH    = 21;
constexpr int HH     = 41;
constexpr int NP     = HH * HH;       // 1681 pixels
constexpr int IW     = 321;           // input image H=W
constexpr int QS     = 32;            // padded channel stride for P/LOGU/QF
constexpr float EPSV = 1e-5f;

constexpr int NROWS  = 1696;          // M rows per batch
constexpr int KPAD   = 1792;          // M cols (bytes) padded to 56*32
constexpr int NKB    = 56;            // K blocks of 32
constexpr int ITL16  = 106;           // 16-row tiles per batch
constexpr int NPIX   = NBATCH * NP;             // 26896
constexpr int LOSS_BLOCKS = (NPIX + 255) / 256; // 106
constexpr int RSB_TILES = (NP + 63) / 64;       // 27
constexpr int BMROWS = 8;
constexpr int BMTILES = (NP + BMROWS - 1) / BMROWS;   // 211

// B-fragment-linear Q storage (fp8): per batch [56 kb][2 ct][64 lane][8 B]
constexpr int QB_BATCH = NKB * 2 * 512;          // 57344 bytes per batch
constexpr int QB_BUF   = NBATCH * QB_BATCH;      // 917504 bytes per buffer
constexpr int RXN = NBATCH * 3 * IW * HH;        // 631728

constexpr float CS_COLOR = 0.06533245f;   // sqrt(log2(e)/338)
constexpr float CS_XY    = 0.12739827f;   // sqrt(0.01125*log2(e))
constexpr float L2E8     = 11.5415603f;   // 8*log2(e)
constexpr float HLOG2_10 = 1.6609640474f; // 0.5*log2(10)

// workspace offsets in floats
constexpr size_t OFF_W    = 0;                   // 13184
constexpr size_t OFF_RX   = 13184;               // 631744
constexpr size_t OFF_COL  = 644928;              // scaled colors + log-weight w [npix][4]
constexpr size_t OFF_P    = 752512;              // 860672
constexpr size_t OFF_LOGU = 1613184;             // 860672
constexpr size_t OFF_QF   = 2473856;             // 860672
constexpr size_t OFF_RSG  = 3334528;             // 1728
constexpr size_t OFF_XY   = 3336256;             // 3456
constexpr size_t OFF_PART = 3339712;             // 256
constexpr size_t OFF_QB   = 3339968;             // 2 fp8 buffers = 458752 floats
constexpr size_t OFF_M    = 3798720;             // fp8 M [16][1696][1792 B]
// total ~63.8 MB

constexpr size_t QB_ZERO_DWORDS = 458752;        // both QB buffers, dwords

__device__ __forceinline__ float wave_sum(float v) {
  #pragma unroll
  for (int off = 32; off > 0; off >>= 1) v += __shfl_down(v, off, 64);
  return v;
}

__device__ __forceinline__ uchar_t f32_to_fp8(float f) {
  return (uchar_t)(__builtin_amdgcn_cvt_pk_fp8_f32(f, f, 0, false) & 0xff);
}

__global__ void k_zero(uint_t* __restrict__ p) {
  size_t t = (size_t)blockIdx.x * blockDim.x + threadIdx.x;
  if (t < QB_ZERO_DWORDS) p[t] = 0u;
}

// K1: jax.image.resize 'linear' (antialias) weight matrix, 321 -> 41.
__global__ void k_weights(float* __restrict__ W) {
  int o = threadIdx.x;
  if (o >= HH) return;
  const float inv = (float)IW / (float)HH;
  float s = (o + 0.5f) * inv - 0.5f;
  float tot = 0.f;
  for (int i = 0; i < IW; ++i) {
    float x = fabsf(s - (float)i) / inv;
    tot += fmaxf(0.f, 1.f - x);
  }
  float r = 1.f / tot;
  for (int i = 0; i < IW; ++i) {
    float x = fabsf(s - (float)i) / inv;
    W[o * IW + i] = fmaxf(0.f, 1.f - x) * r;
  }
}

__global__ void k_xy(float2* __restrict__ XY) {
  int j = blockIdx.x * blockDim.x + threadIdx.x;
  if (j >= NP) return;
  XY[j] = make_float2((float)(j % HH) * CS_XY, (float)(j / HH) * CS_XY);
}

// K2a: separable resize, x pass
__global__ void k_resize_x(const float* __restrict__ img, const float* __restrict__ W,
                           float* __restrict__ RX) {
  int t = blockIdx.x * blockDim.x + threadIdx.x;
  if (t >= RXN) return;
  int xo = t % HH;
  int rest = t / HH;
  int y = rest % IW;
  int nc = rest / IW;
  const float inv = (float)IW / (float)HH;
  float sx = (xo + 0.5f) * inv - 0.5f;
  int xlo = max(0, (int)ceilf(sx - inv)), xhi = min(IW - 1, (int)floorf(sx + inv));
  const float* base = img + ((size_t)nc * IW + y) * IW;
  const float* wr = W + xo * IW;
  float a = 0.f;
  for (int ix = xlo; ix <= xhi; ++ix) a += wr[ix] * base[ix];
  RX[t] = a;
}

// K2b: y pass -> SCALED colors [n][p][4] (w filled later by k_rsb)
__global__ void k_resize_y(const float* __restrict__ RX, const float* __restrict__ W,
                           float* __restrict__ colors) {
  int t = blockIdx.x * blockDim.x + threadIdx.x;
  if (t >= NPIX) return;
  int nb = t / NP, p = t % NP;
  int yo = p / HH, xo = p % HH;
  const float inv = (float)IW / (float)HH;
  float sy = (yo + 0.5f) * inv - 0.5f;
  int ylo = max(0, (int)ceilf(sy - inv)), yhi = min(IW - 1, (int)floorf(sy + inv));
  const float* wr = W + yo * IW;
  float a0 = 0.f, a1 = 0.f, a2 = 0.f;
  const float* b0 = RX + (size_t)(nb * 3 + 0) * IW * HH + xo;
  const float* b1 = RX + (size_t)(nb * 3 + 1) * IW * HH + xo;
  const float* b2 = RX + (size_t)(nb * 3 + 2) * IW * HH + xo;
  for (int iy = ylo; iy <= yhi; ++iy) {
    float wy = wr[iy];
    a0 += wy * b0[(size_t)iy * HH];
    a1 += wy * b1[(size_t)iy * HH];
    a2 += wy * b2[(size_t)iy * HH];
  }
  float* c = colors + (size_t)t * 4;
  c[0] = a0 * CS_COLOR; c[1] = a1 * CS_COLOR; c[2] = a2 * CS_COLOR; c[3] = 0.f;
}

// K3: clamped channel softmax -> P, LOGU, initial fp8 B-fragments
__global__ void k_probs(const float* __restrict__ pred, float* __restrict__ P,
                        float* __restrict__ LOGU, uchar_t* __restrict__ QB) {
  int t = blockIdx.x * blockDim.x + threadIdx.x;
  if (t >= NPIX) return;
  int nb = t / NP, i = t % NP;
  const float* src = pred + (size_t)nb * NCH * NP + i;
  float v[NCH];
  float m = -1e30f;
  #pragma unroll
  for (int c = 0; c < NCH; ++c) { v[c] = src[(size_t)c * NP]; m = fmaxf(m, v[c]); }
  float s = 0.f;
  #pragma unroll
  for (int c = 0; c < NCH; ++c) { v[c] = expf(v[c] - m); s += v[c]; }
  float r = 1.f / s;
  float s2 = 0.f;
  #pragma unroll
  for (int c = 0; c < NCH; ++c) { v[c] = fminf(fmaxf(v[c] * r, EPSV), 1.0f); s2 += v[c]; }
  float r2 = 1.f / s2;
  float* dp = P + (size_t)t * QS;
  float* dl = LOGU + (size_t)t * QS;
  int kb = i >> 5, kr = i & 31, q2 = kr >> 3, j = kr & 7;
  size_t sb = (size_t)nb * QB_BATCH + (size_t)kb * 1024 + j;
  #pragma unroll
  for (int c = 0; c < NCH; ++c) {
    float p = v[c] * r2;
    dp[c] = p; dl[c] = logf(p);
    int ct = c >> 4;
    QB[sb + (size_t)ct * 512 + (q2 * 16 + (c & 15)) * 8] = f32_to_fp8(p);
  }
}

// K4: Gaussian row sums: rsg[i] = 1/sqrt(sum_{j!=i} exp(-8*d2))
__global__ void k_rsg(float* __restrict__ rsg) {
  int i = blockIdx.x;
  int lane = threadIdx.x;
  int xi = i % HH, yi = i / HH;
  float s = 0.f;
  for (int j = lane; j < NP; j += 64) {
    if (j == i) continue;
    int xj = j % HH, yj = j / HH;
    float dx = (float)(xi - xj), dy = (float)(yi - yj);
    s += __builtin_amdgcn_exp2f(-L2E8 * (dx * dx + dy * dy));
  }
  s = wave_sum(s);
  if (lane == 0) rsg[i] = 1.f / sqrtf(s);
}

// K5: bilateral row sums -> COL.w = log2(sqrt(10)*rsb_i)  (LDS-tiled)
__global__ __launch_bounds__(512) void k_rsb(float4* __restrict__ COL,
                                             const float2* __restrict__ XY) {
  __shared__ float S8[NP * 8];
  __shared__ float Red2[8 * 64];
  const int nb = blockIdx.x / RSB_TILES;
  const int i0 = (blockIdx.x % RSB_TILES) * 64;
  const int tid = (int)threadIdx.x;
  const int lane = tid & 63, wv = tid >> 6;

  const float4* colb = COL + (size_t)nb * NP;
  for (int j = tid; j < NP; j += 512) {
    float4 c = colb[j];
    float2 xy = XY[j];
    *(float4*)&S8[j * 8]     = make_float4(c.x, c.y, c.z, 0.f);
    *(float4*)&S8[j * 8 + 4] = make_float4(xy.x, xy.y, 0.f, 0.f);
  }
  __syncthreads();

  const int i = i0 + lane;
  const int im = min(i, NP - 1);
  const float ci0 = S8[im * 8], ci1 = S8[im * 8 + 1], ci2 = S8[im * 8 + 2];
  const float xi = S8[im * 8 + 4], yi = S8[im * 8 + 5];

  float s = 0.f;
  for (int j = wv; j < NP; j += 8) {
    float4 a = *(const float4*)&S8[j * 8];
    float4 b = *(const float4*)&S8[j * 8 + 4];
    float dx = xi - b.x, dy = yi - b.y;
    float acc = dx * dx;
    acc = fmaf(dy, dy, acc);
    float e0 = ci0 - a.x, e1 = ci1 - a.y, e2 = ci2 - a.z;
    acc = fmaf(e0, e0, acc);
    acc = fmaf(e1, e1, acc);
    acc = fmaf(e2, e2, acc);
    s += __builtin_amdgcn_exp2f(-acc);
  }
  Red2[wv * 64 + lane] = s;
  __syncthreads();
  if (wv == 0 && i < NP) {
    float t = -1.0f;   // remove self term
    #pragma unroll
    for (int w = 0; w < 8; ++w) t += Red2[w * 64 + lane];
    // log2(sqrt(10) * 1/sqrt(t)) = 0.5*log2(10) - 0.5*log2(t)
    ((float*)(COL + (size_t)nb * NP + i))[3] = HLOG2_10 - 0.5f * __builtin_amdgcn_logf(t);
  }
}

// K6: M[n][i][j] fp8. 8-row register tile per block: COL/XY read once per 8 rows.
// Bilateral main loop: val = exp2(wi + wj - dist5d) (one exp2, no muls).
// Gaussian added exactly afterwards on the 5x5 neighborhood (support of exp(-8 d2)).
__global__ __launch_bounds__(256) void k_buildM(const float4* __restrict__ COL,
                                                const float2* __restrict__ XY,
                                                const float* __restrict__ rsg,
                                                uchar_t* __restrict__ M) {
  const int nb = blockIdx.x / BMTILES;
  const int i0 = (blockIdx.x % BMTILES) * BMROWS;
  const int tid = (int)threadIdx.x;
  const int nr = min(BMROWS, NP - i0);

  float cx[BMROWS], cy[BMROWS], cz[BMROWS], wi[BMROWS], xi[BMROWS], yi[BMROWS];
  #pragma unroll
  for (int r = 0; r < BMROWS; ++r) {
    int i = min(i0 + r, NP - 1);
    float4 c = COL[(size_t)nb * NP + i];
    float2 xy = XY[i];
    cx[r] = c.x; cy[r] = c.y; cz[r] = c.z; wi[r] = c.w; xi[r] = xy.x; yi[r] = xy.y;
  }
  const float4* colb = COL + (size_t)nb * NP;
  uchar_t* Mb = M + (size_t)(nb * NROWS + i0) * KPAD;

  for (int p = tid; p < 424; p += 256) {
    int j0 = 4 * p;
    float4 cj[4]; float2 xyj[4];
    #pragma unroll
    for (int e = 0; e < 4; ++e) {
      int jc = min(j0 + e, NP - 1);
      cj[e] = colb[jc];
      xyj[e] = XY[jc];
    }
    for (int r = 0; r < nr; ++r) {
      float v[4];
      #pragma unroll
      for (int e = 0; e < 4; ++e) {
        float dx = xi[r] - xyj[e].x, dy = yi[r] - xyj[e].y;
        float acc = wi[r] + cj[e].w;
        acc = fmaf(-dx, dx, acc);
        acc = fmaf(-dy, dy, acc);
        float e0 = cx[r] - cj[e].x, e1 = cy[r] - cj[e].y, e2 = cz[r] - cj[e].z;
        acc = fmaf(-e0, e0, acc);
        acc = fmaf(-e1, e1, acc);
        acc = fmaf(-e2, e2, acc);
        float val = __builtin_amdgcn_exp2f(acc);
        int je = j0 + e;
        v[e] = (je < NP && je != i0 + r) ? val : 0.f;
      }
      uint_t wrd = __builtin_amdgcn_cvt_pk_fp8_f32(v[0], v[1], 0, false);
      wrd = __builtin_amdgcn_cvt_pk_fp8_f32(v[2], v[3], (int)wrd, true);
      *(uint_t*)(Mb + (size_t)r * KPAD + 4 * p) = wrd;
    }
  }
  // zero pad cols [1696, 1792): 24 dwords per row
  if (tid < nr * 24) {
    int r = tid / 24, d = tid % 24;
    *(uint_t*)(Mb + (size_t)r * KPAD + 1696 + 4 * d) = 0u;
  }
  __syncthreads();   // drains stores (vmcnt0) -> safe byte overwrite below
  // exact Gaussian add on 5x5 neighborhood
  if (tid < nr * 25) {
    int r = tid / 25, n = tid % 25;
    int i = i0 + r;
    int dxp = n % 5 - 2, dyp = n / 5 - 2;
    int xpi = i % HH, ypi = i / HH;
    int xj = xpi + dxp, yj = ypi + dyp;
    if ((dxp | dyp) != 0 && xj >= 0 && xj < HH && yj >= 0 && yj < HH) {
      int j = yj * HH + xj;
      float d2 = (float)(dxp * dxp + dyp * dyp);
      float kg = 3.f * rsg[i] * rsg[j] * __builtin_amdgcn_exp2f(-L2E8 * d2);
      float4 c = colb[j];
      float2 xy = XY[j];
      float dx = xi[r] - xy.x, dy = yi[r] - xy.y;
      float acc = wi[r] + c.w;
      acc = fmaf(-dx, dx, acc);
      acc = fmaf(-dy, dy, acc);
      float e0 = cx[r] - c.x, e1 = cy[r] - c.y, e2 = cz[r] - c.z;
      acc = fmaf(-e0, e0, acc);
      acc = fmaf(-e1, e1, acc);
      acc = fmaf(-e2, e2, acc);
      float val = __builtin_amdgcn_exp2f(acc) + kg;
      Mb[(size_t)r * KPAD + j] = f32_to_fp8(val);
    }
  }
}

// K7: one mean-field iteration — barrier-free fp8 MFMA streaming GEMV.
// 1 wave per block, 16 rows, full K; A per-lane dwordx2 loads (L1 sector reuse
// across kb pairs), B from XCD-pinned hot L2. No LDS, no __syncthreads.
// Grid swizzle: blockIdx = tile*16 + nb -> batch nb pinned to XCD nb%8.
__global__ __launch_bounds__(64) void k_iter(const uchar_t* __restrict__ M,
                                             const uchar_t* __restrict__ QBin,
                                             uchar_t* __restrict__ QBout,
                                             const float* __restrict__ LOGU,
                                             float* __restrict__ QF) {
  const int nb = blockIdx.x & 15;
  const int t0 = (blockIdx.x >> 4) * 16;
  const int lane = (int)threadIdx.x;
  const int mrow = lane & 15, quad = lane >> 4;

  f32x4 acc0 = {0.f, 0.f, 0.f, 0.f};    // ch 0..15
  f32x4 acc1 = {0.f, 0.f, 0.f, 0.f};    // ch 16..20

  const uchar_t* Ap = M + (size_t)(nb * NROWS + t0 + mrow) * KPAD + quad * 8;
  const uchar_t* Bp = QBin + (size_t)nb * QB_BATCH + lane * 8;

  #pragma unroll 8
  for (int kb = 0; kb < NKB; ++kb) {
    long a  = *(const long*)(Ap);
    long b0 = *(const long*)(Bp);
    long b1 = *(const long*)(Bp + 512);
    Ap += 32; Bp += 1024;
    acc0 = __builtin_amdgcn_mfma_f32_16x16x32_fp8_fp8(a, b0, acc0, 0, 0, 0);
    acc1 = __builtin_amdgcn_mfma_f32_16x16x32_fp8_fp8(a, b1, acc1, 0, 0, 0);
  }

  const bool c1ok = (mrow + 16) < NCH;
  #pragma unroll
  for (int reg = 0; reg < 4; ++reg) {
    int r = t0 + quad * 4 + reg;
    int rg = nb * NP + min(r, NP - 1);
    float tv0 = LOGU[(size_t)rg * QS + mrow] + acc0[reg];
    float tv1 = c1ok ? (LOGU[(size_t)rg * QS + 16 + mrow] + acc1[reg]) : -1e30f;
    float mx = fmaxf(tv0, tv1);
    mx = fmaxf(mx, __shfl_xor(mx, 1));
    mx = fmaxf(mx, __shfl_xor(mx, 2));
    mx = fmaxf(mx, __shfl_xor(mx, 4));
    mx = fmaxf(mx, __shfl_xor(mx, 8));
    float e0 = __expf(tv0 - mx);
    float e1 = c1ok ? __expf(tv1 - mx) : 0.f;
    float sm = e0 + e1;
    sm += __shfl_xor(sm, 1);
    sm += __shfl_xor(sm, 2);
    sm += __shfl_xor(sm, 4);
    sm += __shfl_xor(sm, 8);
    float rinv = 1.f / sm;
    if (r < NP) {
      int kb = r >> 5, kr = r & 31, q2 = kr >> 3, j = kr & 7;
      size_t sbo = (size_t)nb * QB_BATCH + (size_t)kb * 1024 + (q2 * 16 + mrow) * 8 + j;
      float q0 = e0 * rinv;
      QF[(size_t)(nb * NP + r) * QS + mrow] = q0;
      QBout[sbo] = f32_to_fp8(q0);
      if (c1ok) {
        float q1 = e1 * rinv;
        QF[(size_t)(nb * NP + r) * QS + 16 + mrow] = q1;
        QBout[sbo + 512] = f32_to_fp8(q1);
      }
    }
  }
}

// K8: per-pixel loss contribution
__global__ void k_loss(const float* __restrict__ Qf, const float* __restrict__ P,
                       float* __restrict__ part) {
  int t = blockIdx.x * blockDim.x + threadIdx.x;
  float s = 0.f;
  if (t < NPIX) {
    const float* q = Qf + (size_t)t * QS;
    const float* p = P + (size_t)t * QS;
    float qv[NCH];
    float qsum = 0.f;
    #pragma unroll
    for (int c = 0; c < NCH; ++c) { qv[c] = fmaxf(q[c], EPSV); qsum += qv[c]; }
    float r = 1.f / qsum;
    #pragma unroll
    for (int c = 0; c < NCH; ++c) {
      float qs = qv[c] * r;
      float ratio = fminf(fmaxf(qs / p[c], 0.05f), 20.0f);
      s += qs * logf(ratio);
    }
  }
  __shared__ float red[256];
  red[threadIdx.x] = s;
  __syncthreads();
  for (int st = 128; st > 0; st >>= 1) {
    if ((int)threadIdx.x < st) red[threadIdx.x] += red[threadIdx.x + st];
    __syncthreads();
  }
  if (threadIdx.x == 0) part[blockIdx.x] = red[0];
}

// K9: final reduction -> d_out[0]
__global__ void k_final(const float* __restrict__ part, float* __restrict__ out) {
  float s = 0.f;
  for (int k = threadIdx.x; k < LOSS_BLOCKS; k += 64) s += part[k];
  s = wave_sum(s);
  if (threadIdx.x == 0) out[0] = s / (float)NPIX;
}

}  // namespace

extern "C" void kernel_launch(void* const* d_in, const int* in_sizes, int n_in,
                              void* d_out, int out_size, void* d_ws, size_t ws_size,
                              hipStream_t stream) {
  const float* images  = (const float*)d_in[0];   // (16,3,321,321) fp32
  const float* predict = (const float*)d_in[1];   // (16,21,41,41) fp32
  float* out = (float*)d_out;
  float* ws = (float*)d_ws;

  float*  W    = ws + OFF_W;
  float*  RX   = ws + OFF_RX;
  float4* COL  = (float4*)(ws + OFF_COL);
  float*  P    = ws + OFF_P;
  float*  LOGU = ws + OFF_LOGU;
  float*  QF   = ws + OFF_QF;
  float*  RSG  = ws + OFF_RSG;
  float2* XY   = (float2*)(ws + OFF_XY);
  float*  PART = ws + OFF_PART;
  uchar_t* QB_A = (uchar_t*)(ws + OFF_QB);
  uchar_t* QB_B = QB_A + (size_t)QB_BUF;
  uchar_t* M    = (uchar_t*)(ws + OFF_M);

  hipLaunchKernelGGL(k_zero, dim3((unsigned)((QB_ZERO_DWORDS + 255) / 256)), dim3(256), 0,
                     stream, (uint_t*)QB_A);
  hipLaunchKernelGGL(k_weights, dim3(1), dim3(64), 0, stream, W);
  hipLaunchKernelGGL(k_xy, dim3((NP + 255) / 256), dim3(256), 0, stream, XY);
  hipLaunchKernelGGL(k_resize_x, dim3((RXN + 255) / 256), dim3(256), 0, stream, images, W, RX);
  hipLaunchKernelGGL(k_resize_y, dim3(LOSS_BLOCKS), dim3(256), 0, stream, RX, W, (float*)COL);
  hipLaunchKernelGGL(k_probs, dim3(LOSS_BLOCKS), dim3(256), 0, stream, predict, P, LOGU, QB_A);
  hipLaunchKernelGGL(k_rsg, dim3(NP), dim3(64), 0, stream, RSG);
  hipLaunchKernelGGL(k_rsb, dim3(NBATCH * RSB_TILES), dim3(512), 0, stream, COL, XY);
  hipLaunchKernelGGL(k_buildM, dim3(NBATCH * BMTILES), dim3(256), 0, stream, COL, XY, RSG, M);

  const uchar_t* qbin = QB_A;
  uchar_t* qbout = QB_B;
  for (int it = 0; it < 10; ++it) {
    hipLaunchKernelGGL(k_iter, dim3(ITL16 * NBATCH), dim3(64), 0, stream,
                       M, qbin, qbout, LOGU, QF);
    const uchar_t* t = qbout; qbout = (uchar_t*)qbin; qbin = t;
  }
  hipLaunchKernelGGL(k_loss, dim3(LOSS_BLOCKS), dim3(256), 0, stream, QF, P, PART);
  hipLaunchKernelGGL(k_final, dim3(1), dim3(64), 0, stream, PART, out);
}

// Round 9
// 359.877 us; speedup vs baseline: 1.2040x; 1.2040x over previous
//
#include <hip/hip_runtime.h>
#include <math.h>

namespace {

typedef unsigned short ushort_t;
typedef unsigned int uint_t;
typedef unsigned char uchar_t;
typedef __attribute__((ext_vector_type(4))) float f32x4;

constexpr int NBATCH = 16;
constexpr int NCH    = 21;
constexpr int HH     = 41;
constexpr int NP     = HH * HH;       // 1681 pixels
constexpr int IW     = 321;           // input image H=W
constexpr int QS     = 32;            // padded channel stride for P/LOGU/QF
constexpr float EPSV = 1e-5f;

constexpr int NKB    = 56;            // K blocks of 32 (53 live + 3 zero-B pads)
constexpr int NTILE  = 106;           // 16-row tiles per batch
constexpr int NPIX   = NBATCH * NP;             // 26896
constexpr int LOSS_BLOCKS = (NPIX + 255) / 256; // 106
constexpr int RSB_TILES = (NP + 63) / 64;       // 27
constexpr int BMROWS = 8;
constexpr int BMTILES = (NP + BMROWS - 1) / BMROWS;   // 211

// A-fragment-linear M: [nb][tile][kb][lane][8B];  per-batch bytes:
constexpr size_t M_BATCH = (size_t)NTILE * NKB * 512;   // 3,039,232 B

// B-fragment-linear Q storage (fp8): per batch [56 kb][2 ct][64 lane][8 B]
constexpr int QB_BATCH = NKB * 2 * 512;          // 57344 bytes per batch
constexpr int QB_BUF   = NBATCH * QB_BATCH;      // 917504 bytes per buffer
constexpr int RXN = NBATCH * 3 * IW * HH;        // 631728

constexpr float CS_COLOR = 0.06533245f;   // sqrt(log2(e)/338)
constexpr float CS_XY    = 0.12739827f;   // sqrt(0.01125*log2(e))
constexpr float L2E8     = 11.5415603f;   // 8*log2(e)
constexpr float HLOG2_10 = 1.6609640474f; // 0.5*log2(10)

// workspace offsets in floats
constexpr size_t OFF_W    = 0;                   // 13184
constexpr size_t OFF_RX   = 13184;               // 631744
constexpr size_t OFF_COL  = 644928;              // scaled colors + log-weight w [npix][4]
constexpr size_t OFF_P    = 752512;              // 860672
constexpr size_t OFF_LOGU = 1613184;             // 860672
constexpr size_t OFF_QF   = 2473856;             // 860672
constexpr size_t OFF_RSG  = 3334528;             // 1728
constexpr size_t OFF_XY   = 3336256;             // 3456
constexpr size_t OFF_PART = 3339712;             // 256
constexpr size_t OFF_QB   = 3339968;             // 2 fp8 buffers = 458752 floats
constexpr size_t OFF_M    = 3798720;             // fp8 M frag [16][106][56][64][8]
// total ~63.8 MB

constexpr size_t QB_ZERO_DWORDS = 458752;        // both QB buffers, dwords

__device__ __forceinline__ float wave_sum(float v) {
  #pragma unroll
  for (int off = 32; off > 0; off >>= 1) v += __shfl_down(v, off, 64);
  return v;
}

__device__ __forceinline__ uchar_t f32_to_fp8(float f) {
  return (uchar_t)(__builtin_amdgcn_cvt_pk_fp8_f32(f, f, 0, false) & 0xff);
}

__global__ void k_zero(uint_t* __restrict__ p) {
  size_t t = (size_t)blockIdx.x * blockDim.x + threadIdx.x;
  if (t < QB_ZERO_DWORDS) p[t] = 0u;
}

// K1: jax.image.resize 'linear' (antialias) weight matrix, 321 -> 41.
__global__ void k_weights(float* __restrict__ W) {
  int o = threadIdx.x;
  if (o >= HH) return;
  const float inv = (float)IW / (float)HH;
  float s = (o + 0.5f) * inv - 0.5f;
  float tot = 0.f;
  for (int i = 0; i < IW; ++i) {
    float x = fabsf(s - (float)i) / inv;
    tot += fmaxf(0.f, 1.f - x);
  }
  float r = 1.f / tot;
  for (int i = 0; i < IW; ++i) {
    float x = fabsf(s - (float)i) / inv;
    W[o * IW + i] = fmaxf(0.f, 1.f - x) * r;
  }
}

__global__ void k_xy(float2* __restrict__ XY) {
  int j = blockIdx.x * blockDim.x + threadIdx.x;
  if (j >= NP) return;
  XY[j] = make_float2((float)(j % HH) * CS_XY, (float)(j / HH) * CS_XY);
}

// K2a: separable resize, x pass
__global__ void k_resize_x(const float* __restrict__ img, const float* __restrict__ W,
                           float* __restrict__ RX) {
  int t = blockIdx.x * blockDim.x + threadIdx.x;
  if (t >= RXN) return;
  int xo = t % HH;
  int rest = t / HH;
  int y = rest % IW;
  int nc = rest / IW;
  const float inv = (float)IW / (float)HH;
  float sx = (xo + 0.5f) * inv - 0.5f;
  int xlo = max(0, (int)ceilf(sx - inv)), xhi = min(IW - 1, (int)floorf(sx + inv));
  const float* base = img + ((size_t)nc * IW + y) * IW;
  const float* wr = W + xo * IW;
  float a = 0.f;
  for (int ix = xlo; ix <= xhi; ++ix) a += wr[ix] * base[ix];
  RX[t] = a;
}

// K2b: y pass -> SCALED colors [n][p][4] (w filled later by k_rsb)
__global__ void k_resize_y(const float* __restrict__ RX, const float* __restrict__ W,
                           float* __restrict__ colors) {
  int t = blockIdx.x * blockDim.x + threadIdx.x;
  if (t >= NPIX) return;
  int nb = t / NP, p = t % NP;
  int yo = p / HH, xo = p % HH;
  const float inv = (float)IW / (float)HH;
  float sy = (yo + 0.5f) * inv - 0.5f;
  int ylo = max(0, (int)ceilf(sy - inv)), yhi = min(IW - 1, (int)floorf(sy + inv));
  const float* wr = W + yo * IW;
  float a0 = 0.f, a1 = 0.f, a2 = 0.f;
  const float* b0 = RX + (size_t)(nb * 3 + 0) * IW * HH + xo;
  const float* b1 = RX + (size_t)(nb * 3 + 1) * IW * HH + xo;
  const float* b2 = RX + (size_t)(nb * 3 + 2) * IW * HH + xo;
  for (int iy = ylo; iy <= yhi; ++iy) {
    float wy = wr[iy];
    a0 += wy * b0[(size_t)iy * HH];
    a1 += wy * b1[(size_t)iy * HH];
    a2 += wy * b2[(size_t)iy * HH];
  }
  float* c = colors + (size_t)t * 4;
  c[0] = a0 * CS_COLOR; c[1] = a1 * CS_COLOR; c[2] = a2 * CS_COLOR; c[3] = 0.f;
}

// K3: clamped channel softmax -> P, LOGU, initial fp8 B-fragments
__global__ void k_probs(const float* __restrict__ pred, float* __restrict__ P,
                        float* __restrict__ LOGU, uchar_t* __restrict__ QB) {
  int t = blockIdx.x * blockDim.x + threadIdx.x;
  if (t >= NPIX) return;
  int nb = t / NP, i = t % NP;
  const float* src = pred + (size_t)nb * NCH * NP + i;
  float v[NCH];
  float m = -1e30f;
  #pragma unroll
  for (int c = 0; c < NCH; ++c) { v[c] = src[(size_t)c * NP]; m = fmaxf(m, v[c]); }
  float s = 0.f;
  #pragma unroll
  for (int c = 0; c < NCH; ++c) { v[c] = expf(v[c] - m); s += v[c]; }
  float r = 1.f / s;
  float s2 = 0.f;
  #pragma unroll
  for (int c = 0; c < NCH; ++c) { v[c] = fminf(fmaxf(v[c] * r, EPSV), 1.0f); s2 += v[c]; }
  float r2 = 1.f / s2;
  float* dp = P + (size_t)t * QS;
  float* dl = LOGU + (size_t)t * QS;
  int kb = i >> 5, kr = i & 31, q2 = kr >> 3, j = kr & 7;
  size_t sb = (size_t)nb * QB_BATCH + (size_t)kb * 1024 + j;
  #pragma unroll
  for (int c = 0; c < NCH; ++c) {
    float p = v[c] * r2;
    dp[c] = p; dl[c] = logf(p);
    int ct = c >> 4;
    QB[sb + (size_t)ct * 512 + (q2 * 16 + (c & 15)) * 8] = f32_to_fp8(p);
  }
}

// K4: Gaussian row sums: rsg[i] = 1/sqrt(sum_{j!=i} exp(-8*d2))
__global__ void k_rsg(float* __restrict__ rsg) {
  int i = blockIdx.x;
  int lane = threadIdx.x;
  int xi = i % HH, yi = i / HH;
  float s = 0.f;
  for (int j = lane; j < NP; j += 64) {
    if (j == i) continue;
    int xj = j % HH, yj = j / HH;
    float dx = (float)(xi - xj), dy = (float)(yi - yj);
    s += __builtin_amdgcn_exp2f(-L2E8 * (dx * dx + dy * dy));
  }
  s = wave_sum(s);
  if (lane == 0) rsg[i] = 1.f / sqrtf(s);
}

// K5: bilateral row sums -> COL.w = log2(sqrt(10)*rsb_i)  (LDS-tiled)
__global__ __launch_bounds__(512) void k_rsb(float4* __restrict__ COL,
                                             const float2* __restrict__ XY) {
  __shared__ float S8[NP * 8];
  __shared__ float Red2[8 * 64];
  const int nb = blockIdx.x / RSB_TILES;
  const int i0 = (blockIdx.x % RSB_TILES) * 64;
  const int tid = (int)threadIdx.x;
  const int lane = tid & 63, wv = tid >> 6;

  const float4* colb = COL + (size_t)nb * NP;
  for (int j = tid; j < NP; j += 512) {
    float4 c = colb[j];
    float2 xy = XY[j];
    *(float4*)&S8[j * 8]     = make_float4(c.x, c.y, c.z, 0.f);
    *(float4*)&S8[j * 8 + 4] = make_float4(xy.x, xy.y, 0.f, 0.f);
  }
  __syncthreads();

  const int i = i0 + lane;
  const int im = min(i, NP - 1);
  const float ci0 = S8[im * 8], ci1 = S8[im * 8 + 1], ci2 = S8[im * 8 + 2];
  const float xi = S8[im * 8 + 4], yi = S8[im * 8 + 5];

  float s = 0.f;
  for (int j = wv; j < NP; j += 8) {
    float4 a = *(const float4*)&S8[j * 8];
    float4 b = *(const float4*)&S8[j * 8 + 4];
    float dx = xi - b.x, dy = yi - b.y;
    float acc = dx * dx;
    acc = fmaf(dy, dy, acc);
    float e0 = ci0 - a.x, e1 = ci1 - a.y, e2 = ci2 - a.z;
    acc = fmaf(e0, e0, acc);
    acc = fmaf(e1, e1, acc);
    acc = fmaf(e2, e2, acc);
    s += __builtin_amdgcn_exp2f(-acc);
  }
  Red2[wv * 64 + lane] = s;
  __syncthreads();
  if (wv == 0 && i < NP) {
    float t = -1.0f;   // remove self term
    #pragma unroll
    for (int w = 0; w < 8; ++w) t += Red2[w * 64 + lane];
    ((float*)(COL + (size_t)nb * NP + i))[3] = HLOG2_10 - 0.5f * __builtin_amdgcn_logf(t);
  }
}

// K6: fp8 M in A-FRAGMENT-LINEAR layout [tile][kb][lane=quad*16+mrow][8B].
// 8-row register tile; 8-wide j chunks => one dwordx2 store per (row, chunk).
// Bilateral: exp2(wi+wj-dist5d). Gaussian added exactly on 5x5 fixup pass.
// kb 53..55 unwritten (B is zero there); rows >= NP unwritten (discarded in k_iter).
__global__ __launch_bounds__(256) void k_buildM(const float4* __restrict__ COL,
                                                const float2* __restrict__ XY,
                                                const float* __restrict__ rsg,
                                                uchar_t* __restrict__ M) {
  const int nb = blockIdx.x / BMTILES;
  const int i0 = (blockIdx.x % BMTILES) * BMROWS;
  const int tid = (int)threadIdx.x;
  const int nr = min(BMROWS, NP - i0);
  const int tile = i0 >> 4;            // all 8 rows in one 16-row tile half
  const int mbase = i0 & 15;

  float cx[BMROWS], cy[BMROWS], cz[BMROWS], wi[BMROWS], xi[BMROWS], yi[BMROWS];
  #pragma unroll
  for (int r = 0; r < BMROWS; ++r) {
    int i = min(i0 + r, NP - 1);
    float4 c = COL[(size_t)nb * NP + i];
    float2 xy = XY[i];
    cx[r] = c.x; cy[r] = c.y; cz[r] = c.z; wi[r] = c.w; xi[r] = xy.x; yi[r] = xy.y;
  }
  const float4* colb = COL + (size_t)nb * NP;
  uchar_t* Mb = M + (size_t)nb * M_BATCH + (size_t)tile * (NKB * 512);

  // main pass: chunks of 8 consecutive j (= one lane k-slice). 212 chunks cover kb 0..52.
  for (int p = tid; p < 212; p += 256) {
    const int j0 = 8 * p;
    const int kb = p >> 2, quad = p & 3;
    float4 cj[8]; float2 xyj[8];
    #pragma unroll
    for (int e = 0; e < 8; ++e) {
      int jc = min(j0 + e, NP - 1);
      cj[e] = colb[jc];
      xyj[e] = XY[jc];
    }
    uchar_t* dst = Mb + (size_t)kb * 512 + (quad * 16 + mbase) * 8;
    for (int r = 0; r < nr; ++r) {
      float v[8];
      #pragma unroll
      for (int e = 0; e < 8; ++e) {
        float dx = xi[r] - xyj[e].x, dy = yi[r] - xyj[e].y;
        float acc = wi[r] + cj[e].w;
        acc = fmaf(-dx, dx, acc);
        acc = fmaf(-dy, dy, acc);
        float e0 = cx[r] - cj[e].x, e1 = cy[r] - cj[e].y, e2 = cz[r] - cj[e].z;
        acc = fmaf(-e0, e0, acc);
        acc = fmaf(-e1, e1, acc);
        acc = fmaf(-e2, e2, acc);
        float val = __builtin_amdgcn_exp2f(acc);
        int je = j0 + e;
        v[e] = (je < NP && je != i0 + r) ? val : 0.f;
      }
      uint2 wrd;
      wrd.x = __builtin_amdgcn_cvt_pk_fp8_f32(v[0], v[1], 0, false);
      wrd.x = __builtin_amdgcn_cvt_pk_fp8_f32(v[2], v[3], (int)wrd.x, true);
      wrd.y = __builtin_amdgcn_cvt_pk_fp8_f32(v[4], v[5], 0, false);
      wrd.y = __builtin_amdgcn_cvt_pk_fp8_f32(v[6], v[7], (int)wrd.y, true);
      *(uint2*)(dst + (size_t)r * 8) = wrd;
    }
  }
  __syncthreads();   // drains stores (compiler emits vmcnt(0) before s_barrier)
  // exact Gaussian add on 5x5 neighborhood (support of exp(-8 d2))
  if (tid < nr * 25) {
    int r = tid / 25, n = tid % 25;
    int i = i0 + r;
    int dxp = n % 5 - 2, dyp = n / 5 - 2;
    int xpi = i % HH, ypi = i / HH;
    int xj = xpi + dxp, yj = ypi + dyp;
    if ((dxp | dyp) != 0 && xj >= 0 && xj < HH && yj >= 0 && yj < HH) {
      int j = yj * HH + xj;
      float d2 = (float)(dxp * dxp + dyp * dyp);
      float kg = 3.f * rsg[i] * rsg[j] * __builtin_amdgcn_exp2f(-L2E8 * d2);
      float4 c = colb[j];
      float2 xy = XY[j];
      float dx = xi[r] - xy.x, dy = yi[r] - xy.y;
      float acc = wi[r] + c.w;
      acc = fmaf(-dx, dx, acc);
      acc = fmaf(-dy, dy, acc);
      float e0 = cx[r] - c.x, e1 = cy[r] - c.y, e2 = cz[r] - c.z;
      acc = fmaf(-e0, e0, acc);
      acc = fmaf(-e1, e1, acc);
      acc = fmaf(-e2, e2, acc);
      float val = __builtin_amdgcn_exp2f(acc) + kg;
      // fragment byte address for (row i, col j)
      size_t a = (size_t)(j >> 5) * 512 + (((j >> 3) & 3) * 16 + (mbase + r)) * 8 + (j & 7);
      Mb[a] = f32_to_fp8(val);
    }
  }
}

// K7: one mean-field iteration — barrier-free fp8 MFMA streaming GEMV.
// 1 wave per block, 16 rows, full K; A fragment-linear => 512 B coalesced per kb.
// Grid swizzle: blockIdx = tile*16 + nb -> batch nb pinned to XCD nb%8.
__global__ __launch_bounds__(64) void k_iter(const uchar_t* __restrict__ M,
                                             const uchar_t* __restrict__ QBin,
                                             uchar_t* __restrict__ QBout,
                                             const float* __restrict__ LOGU,
                                             float* __restrict__ QF) {
  const int nb = blockIdx.x & 15;
  const int tile = blockIdx.x >> 4;
  const int t0 = tile * 16;
  const int lane = (int)threadIdx.x;
  const int mrow = lane & 15, quad = lane >> 4;

  f32x4 acc0 = {0.f, 0.f, 0.f, 0.f};    // ch 0..15
  f32x4 acc1 = {0.f, 0.f, 0.f, 0.f};    // ch 16..20

  const uchar_t* Ap = M + (size_t)nb * M_BATCH + (size_t)tile * (NKB * 512) + lane * 8;
  const uchar_t* Bp = QBin + (size_t)nb * QB_BATCH + lane * 8;

  #pragma unroll 8
  for (int kb = 0; kb < NKB; ++kb) {
    long a  = *(const long*)(Ap);
    long b0 = *(const long*)(Bp);
    long b1 = *(const long*)(Bp + 512);
    Ap += 512; Bp += 1024;
    acc0 = __builtin_amdgcn_mfma_f32_16x16x32_fp8_fp8(a, b0, acc0, 0, 0, 0);
    acc1 = __builtin_amdgcn_mfma_f32_16x16x32_fp8_fp8(a, b1, acc1, 0, 0, 0);
  }

  const bool c1ok = (mrow + 16) < NCH;
  #pragma unroll
  for (int reg = 0; reg < 4; ++reg) {
    int r = t0 + quad * 4 + reg;
    int rg = nb * NP + min(r, NP - 1);
    float tv0 = LOGU[(size_t)rg * QS + mrow] + acc0[reg];
    float tv1 = c1ok ? (LOGU[(size_t)rg * QS + 16 + mrow] + acc1[reg]) : -1e30f;
    float mx = fmaxf(tv0, tv1);
    mx = fmaxf(mx, __shfl_xor(mx, 1));
    mx = fmaxf(mx, __shfl_xor(mx, 2));
    mx = fmaxf(mx, __shfl_xor(mx, 4));
    mx = fmaxf(mx, __shfl_xor(mx, 8));
    float e0 = __expf(tv0 - mx);
    float e1 = c1ok ? __expf(tv1 - mx) : 0.f;
    float sm = e0 + e1;
    sm += __shfl_xor(sm, 1);
    sm += __shfl_xor(sm, 2);
    sm += __shfl_xor(sm, 4);
    sm += __shfl_xor(sm, 8);
    float rinv = 1.f / sm;
    if (r < NP) {
      int kb = r >> 5, kr = r & 31, q2 = kr >> 3, j = kr & 7;
      size_t sbo = (size_t)nb * QB_BATCH + (size_t)kb * 1024 + (q2 * 16 + mrow) * 8 + j;
      float q0 = e0 * rinv;
      QF[(size_t)(nb * NP + r) * QS + mrow] = q0;
      QBout[sbo] = f32_to_fp8(q0);
      if (c1ok) {
        float q1 = e1 * rinv;
        QF[(size_t)(nb * NP + r) * QS + 16 + mrow] = q1;
        QBout[sbo + 512] = f32_to_fp8(q1);
      }
    }
  }
}

// K8: per-pixel loss contribution
__global__ void k_loss(const float* __restrict__ Qf, const float* __restrict__ P,
                       float* __restrict__ part) {
  int t = blockIdx.x * blockDim.x + threadIdx.x;
  float s = 0.f;
  if (t < NPIX) {
    const float* q = Qf + (size_t)t * QS;
    const float* p = P + (size_t)t * QS;
    float qv[NCH];
    float qsum = 0.f;
    #pragma unroll
    for (int c = 0; c < NCH; ++c) { qv[c] = fmaxf(q[c], EPSV); qsum += qv[c]; }
    float r = 1.f / qsum;
    #pragma unroll
    for (int c = 0; c < NCH; ++c) {
      float qs = qv[c] * r;
      float ratio = fminf(fmaxf(qs / p[c], 0.05f), 20.0f);
      s += qs * logf(ratio);
    }
  }
  __shared__ float red[256];
  red[threadIdx.x] = s;
  __syncthreads();
  for (int st = 128; st > 0; st >>= 1) {
    if ((int)threadIdx.x < st) red[threadIdx.x] += red[threadIdx.x + st];
    __syncthreads();
  }
  if (threadIdx.x == 0) part[blockIdx.x] = red[0];
}

// K9: final reduction -> d_out[0]
__global__ void k_final(const float* __restrict__ part, float* __restrict__ out) {
  float s = 0.f;
  for (int k = threadIdx.x; k < LOSS_BLOCKS; k += 64) s += part[k];
  s = wave_sum(s);
  if (threadIdx.x == 0) out[0] = s / (float)NPIX;
}

}  // namespace

extern "C" void kernel_launch(void* const* d_in, const int* in_sizes, int n_in,
                              void* d_out, int out_size, void* d_ws, size_t ws_size,
                              hipStream_t stream) {
  const float* images  = (const float*)d_in[0];   // (16,3,321,321) fp32
  const float* predict = (const float*)d_in[1];   // (16,21,41,41) fp32
  float* out = (float*)d_out;
  float* ws = (float*)d_ws;

  float*  W    = ws + OFF_W;
  float*  RX   = ws + OFF_RX;
  float4* COL  = (float4*)(ws + OFF_COL);
  float*  P    = ws + OFF_P;
  float*  LOGU = ws + OFF_LOGU;
  float*  QF   = ws + OFF_QF;
  float*  RSG  = ws + OFF_RSG;
  float2* XY   = (float2*)(ws + OFF_XY);
  float*  PART = ws + OFF_PART;
  uchar_t* QB_A = (uchar_t*)(ws + OFF_QB);
  uchar_t* QB_B = QB_A + (size_t)QB_BUF;
  uchar_t* M    = (uchar_t*)(ws + OFF_M);

  hipLaunchKernelGGL(k_zero, dim3((unsigned)((QB_ZERO_DWORDS + 255) / 256)), dim3(256), 0,
                     stream, (uint_t*)QB_A);
  hipLaunchKernelGGL(k_weights, dim3(1), dim3(64), 0, stream, W);
  hipLaunchKernelGGL(k_xy, dim3((NP + 255) / 256), dim3(256), 0, stream, XY);
  hipLaunchKernelGGL(k_resize_x, dim3((RXN + 255) / 256), dim3(256), 0, stream, images, W, RX);
  hipLaunchKernelGGL(k_resize_y, dim3(LOSS_BLOCKS), dim3(256), 0, stream, RX, W, (float*)COL);
  hipLaunchKernelGGL(k_probs, dim3(LOSS_BLOCKS), dim3(256), 0, stream, predict, P, LOGU, QB_A);
  hipLaunchKernelGGL(k_rsg, dim3(NP), dim3(64), 0, stream, RSG);
  hipLaunchKernelGGL(k_rsb, dim3(NBATCH * RSB_TILES), dim3(512), 0, stream, COL, XY);
  hipLaunchKernelGGL(k_buildM, dim3(NBATCH * BMTILES), dim3(256), 0, stream, COL, XY, RSG, M);

  const uchar_t* qbin = QB_A;
  uchar_t* qbout = QB_B;
  for (int it = 0; it < 10; ++it) {
    hipLaunchKernelGGL(k_iter, dim3(NTILE * NBATCH), dim3(64), 0, stream,
                       M, qbin, qbout, LOGU, QF);
    const uchar_t* t = qbout; qbout = (uchar_t*)qbin; qbin = t;
  }
  hipLaunchKernelGGL(k_loss, dim3(LOSS_BLOCKS), dim3(256), 0, stream, QF, P, PART);
  hipLaunchKernelGGL(k_final, dim3(1), dim3(64), 0, stream, PART, out);
}